// Round 5
// baseline (187.902 us; speedup 1.0000x reference)
//
#include <hip/hip_runtime.h>
#include <hip/hip_bf16.h>
#include <cstdint>

#define DIMSZ 1024
#define S_LEN 2048
#define NH 16
#define HD 64

typedef __attribute__((ext_vector_type(4))) float f32x4;
typedef __attribute__((ext_vector_type(8))) __bf16 bf16x8;

#define MFMA_BF16(a,b,c) __builtin_amdgcn_mfma_f32_16x16x32_bf16((a),(b),(c),0,0,0)

__device__ __forceinline__ void gload_lds16(const void* g, void* l) {
  __builtin_amdgcn_global_load_lds(
      (const __attribute__((address_space(1))) unsigned int*)(uintptr_t)g,
      (__attribute__((address_space(3))) unsigned int*)(uintptr_t)l,
      16, 0, 0);
}

// ---------------- fused cast fp32 -> bf16 for all 4 weights ----------------
__global__ __launch_bounds__(256)
void cast_all_kernel(const float* __restrict__ s0, const float* __restrict__ s1,
                     const float* __restrict__ s2, const float* __restrict__ s3,
                     __hip_bfloat16* __restrict__ d0, __hip_bfloat16* __restrict__ d1,
                     __hip_bfloat16* __restrict__ d2, __hip_bfloat16* __restrict__ d3)
{
  int i = blockIdx.x * 256 + threadIdx.x;   // float4 index, total 2097152
  const float* s; __hip_bfloat16* d; int off;
  if (i < 786432)       { s = s0; d = d0; off = i; }
  else if (i < 1048576) { s = s1; d = d1; off = i - 786432; }
  else if (i < 1572864) { s = s2; d = d2; off = i - 1048576; }
  else                  { s = s3; d = d3; off = i - 1572864; }
  float4 v = ((const float4*)s)[off];
  __hip_bfloat16* o = d + (size_t)off * 4;
  o[0] = __float2bfloat16(v.x);
  o[1] = __float2bfloat16(v.y);
  o[2] = __float2bfloat16(v.z);
  o[3] = __float2bfloat16(v.w);
}

// ---------------- RMSNorm: fp32 row -> bf16 row ----------------
__global__ __launch_bounds__(256)
void rmsnorm_kernel(const float* __restrict__ x, const float* __restrict__ w,
                    __hip_bfloat16* __restrict__ out)
{
  int row = blockIdx.x;
  int tid = threadIdx.x;
  const float4 v = ((const float4*)(x + (size_t)row * DIMSZ))[tid];
  float ss = v.x*v.x + v.y*v.y + v.z*v.z + v.w*v.w;
  #pragma unroll
  for (int m = 32; m >= 1; m >>= 1) ss += __shfl_xor(ss, m);
  __shared__ float red[4];
  int wave = tid >> 6, lane = tid & 63;
  if (lane == 0) red[wave] = ss;
  __syncthreads();
  float tot = red[0] + red[1] + red[2] + red[3];
  float sc = rsqrtf(tot * (1.0f / DIMSZ) + 1e-6f);
  const float4 wv = ((const float4*)w)[tid];
  __hip_bfloat16* o = out + (size_t)row * DIMSZ + tid * 4;
  o[0] = __float2bfloat16(v.x * sc * wv.x);
  o[1] = __float2bfloat16(v.y * sc * wv.y);
  o[2] = __float2bfloat16(v.z * sc * wv.z);
  o[3] = __float2bfloat16(v.w * sc * wv.w);
}

// ---------------- GEMM 256x256, 8-phase (T2+T3+T4+T5), bf16 in, fp32 acc -------
// 512 threads = 8 waves (2M x 4N), per-wave C = 128x64. BK=64, 2 K-tiles/iter,
// 8 phases/iter. LDS 128 KB: A,B each 2 x [256 rows][128 B] (double buffer by
// K-tile parity). Stage via global_load_lds w=16 with inverse-XOR-swizzled
// global source (linear LDS dest); reads XOR the same (row&7)<<4. Counted
// vmcnt(6) at phases 4/8 only (3 half-tiles in flight). B-frags register-held
// per K-tile. setprio(1) around each 16-MFMA cluster.
template<int EPI>
__global__ __launch_bounds__(512, 2)
void gemm256(const __hip_bfloat16* __restrict__ A,
             const __hip_bfloat16* __restrict__ Bw,
             float* __restrict__ Cf, __hip_bfloat16* __restrict__ Cb,
             const float* __restrict__ resid,
             int N, int K, int nbx)
{
  __shared__ __align__(16) char sA[2][32768];
  __shared__ __align__(16) char sB[2][32768];
  const int tid = threadIdx.x;
  const int w = tid >> 6, lane = tid & 63;
  const int lg = lane >> 4, lr = lane & 15;
  const int wr = w >> 2, wc = w & 3;
  // XCD-aware bijective remap (gridDim.x % 8 == 0)
  const int cpx = gridDim.x >> 3;
  const int swb = (blockIdx.x & 7) * cpx + (blockIdx.x >> 3);
  const int bx = swb % nbx, by = swb / nbx;
  const int row0 = by * 256, col0 = bx * 256;

  const size_t Kb = (size_t)K * 2;
  const int rr = tid >> 3;                                  // 0..63
  const int scol = ((tid & 7) << 4) ^ ((rr & 7) << 4);      // pre-swizzled src col
  const char* gA = (const char*)A + (size_t)(row0 + rr) * Kb + scol;
  const char* gB = (const char*)Bw + (size_t)(col0 + rr) * Kb + scol;
  const int wofs = w << 10;

  f32x4 acc[8][4] = {};

#define SA_(buf, kt, hf) do { \
    gload_lds16(gA + (size_t)((hf) * 128) * Kb + (size_t)(kt) * 128, sA[buf] + (hf) * 16384 + wofs); \
    gload_lds16(gA + (size_t)((hf) * 128 + 64) * Kb + (size_t)(kt) * 128, sA[buf] + (hf) * 16384 + 8192 + wofs); \
  } while (0)
#define SB_(buf, kt, hf) do { \
    gload_lds16(gB + (size_t)((hf) * 128) * Kb + (size_t)(kt) * 128, sB[buf] + (hf) * 16384 + wofs); \
    gload_lds16(gB + (size_t)((hf) * 128 + 64) * Kb + (size_t)(kt) * 128, sB[buf] + (hf) * 16384 + 8192 + wofs); \
  } while (0)

  // prologue stream: B0(0),B1(0),A0(0),A1(0),B0(1),B1(1),A0(1)  [A1(1) at ph1]
  SB_(0, 0, 0); SB_(0, 0, 1); SA_(0, 0, 0); SA_(0, 0, 1);
  SB_(1, 1, 0); SB_(1, 1, 1); SA_(1, 1, 0);
  __syncthreads();    // compiler emits vmcnt(0) drain here

  const int swz = (lr & 7) << 4;
  const int ntiles = K >> 6;
  const int niter = ntiles >> 1;
  const int abase = wr * 16384;
  const int bbase = (wc >> 1) * 16384 + ((wc & 1) * 64) * 128;
  const int c0 = (lg * 16) ^ swz;
  const int c1 = (64 + lg * 16) ^ swz;

  bf16x8 br_[4][2];

#define LOADB(par) do { _Pragma("unroll") for (int n = 0; n < 4; ++n) { \
    const char* p = sB[par] + bbase + (n * 16 + lr) * 128; \
    br_[n][0] = *(const bf16x8*)(p + c0); br_[n][1] = *(const bf16x8*)(p + c1); } } while (0)

#define PHASE(par, q, STAGE_STMT) do { \
    bf16x8 a0k0, a0k1, a1k0, a1k1; \
    { const char* p = sA[par] + abase + ((q) * 32 + lr) * 128; \
      a0k0 = *(const bf16x8*)(p + c0); a0k1 = *(const bf16x8*)(p + c1); } \
    { const char* p = sA[par] + abase + ((q) * 32 + 16 + lr) * 128; \
      a1k0 = *(const bf16x8*)(p + c0); a1k1 = *(const bf16x8*)(p + c1); } \
    STAGE_STMT; \
    __builtin_amdgcn_s_barrier(); \
    asm volatile("s_waitcnt lgkmcnt(0)" ::: "memory"); \
    __builtin_amdgcn_sched_barrier(0); \
    __builtin_amdgcn_s_setprio(1); \
    _Pragma("unroll") for (int n = 0; n < 4; ++n) { \
      acc[(q)*2][n]   = MFMA_BF16(a0k0, br_[n][0], acc[(q)*2][n]); \
      acc[(q)*2+1][n] = MFMA_BF16(a1k0, br_[n][0], acc[(q)*2+1][n]); } \
    _Pragma("unroll") for (int n = 0; n < 4; ++n) { \
      acc[(q)*2][n]   = MFMA_BF16(a0k1, br_[n][1], acc[(q)*2][n]); \
      acc[(q)*2+1][n] = MFMA_BF16(a1k1, br_[n][1], acc[(q)*2+1][n]); } \
    __builtin_amdgcn_s_setprio(0); \
    __builtin_amdgcn_s_barrier(); \
  } while (0)

  for (int it = 0; it < niter; ++it) {
    const int T0 = 2 * it, T1 = T0 + 1;
    // --- tile T0 (buf 0), phases 1-4 ---
    LOADB(0);
    PHASE(0, 0, { SA_(1, T1, 1); });                                   // ph1: A1(T1)
    PHASE(0, 1, { if (T0 + 2 < ntiles) SB_(0, T0 + 2, 0); });          // ph2
    PHASE(0, 2, { if (T0 + 2 < ntiles) SB_(0, T0 + 2, 1); });          // ph3
    PHASE(0, 3, { if (T0 + 2 < ntiles) SA_(0, T0 + 2, 0);              // ph4
                  asm volatile("s_waitcnt vmcnt(6)" ::: "memory"); });
    // --- tile T1 (buf 1), phases 5-8 ---
    LOADB(1);
    PHASE(1, 0, { if (T0 + 2 < ntiles) SA_(0, T0 + 2, 1); });          // ph5
    PHASE(1, 1, { if (T1 + 2 < ntiles) SB_(1, T1 + 2, 0); });          // ph6
    PHASE(1, 2, { if (T1 + 2 < ntiles) SB_(1, T1 + 2, 1); });          // ph7
    PHASE(1, 3, { if (T1 + 2 < ntiles) SA_(1, T1 + 2, 0);              // ph8
                  asm volatile("s_waitcnt vmcnt(6)" ::: "memory"); });
  }
#undef SA_
#undef SB_
#undef LOADB
#undef PHASE

  #pragma unroll
  for (int m = 0; m < 8; ++m) {
    #pragma unroll
    for (int n = 0; n < 4; ++n) {
      #pragma unroll
      for (int r = 0; r < 4; ++r) {
        const int grow = row0 + wr * 128 + m * 16 + lg * 4 + r;
        const int gcol = col0 + wc * 64 + n * 16 + lr;
        const size_t idx = (size_t)grow * N + gcol;
        const float v = acc[m][n][r];
        if (EPI == 0) {
          Cb[idx] = __float2bfloat16(v);
        } else if (EPI == 1) {
          Cf[idx] = resid[idx] + v;
        } else {
          Cb[idx] = __float2bfloat16(v / (1.0f + __expf(-v)));
        }
      }
    }
  }
}

// ---------------- GEMM v2: 128x128 2-phase (kept for out/proj: grid >= 256) ----
template<int EPI>
__global__ __launch_bounds__(256, 2)
void gemm_bt2(const __hip_bfloat16* __restrict__ A,
              const __hip_bfloat16* __restrict__ Bw,
              float* __restrict__ Cf,
              __hip_bfloat16* __restrict__ Cb,
              const float* __restrict__ resid,
              int N, int K)
{
  __shared__ __align__(16) char sA[2][16384];   // [128 rows][128 B]
  __shared__ __align__(16) char sB[2][16384];
  const int tid = threadIdx.x;
  const int wave = tid >> 6, lane = tid & 63;
  const int lg = lane >> 4, lr15 = lane & 15;
  const int row0 = blockIdx.y * 128, col0 = blockIdx.x * 128;
  const int wr = wave >> 1, wc = wave & 1;
  f32x4 acc[4][4] = {};

  const size_t Kb = (size_t)K * 2;
  const int rown = tid >> 3;               // 0..31
  const int scol = ((tid & 7) << 4) ^ ((rown & 7) << 4);
  const char* gA = (const char*)A + (size_t)(row0 + rown) * Kb + scol;
  const char* gB = (const char*)Bw + (size_t)(col0 + rown) * Kb + scol;
  const int dbase = wave * 1024;

  const int nsteps = K >> 6;
  int cur = 0;

#define STAGE_G(buf, st) do {                                              \
    const size_t kb_ = (size_t)(st) * 128;                                 \
    _Pragma("unroll")                                                      \
    for (int it = 0; it < 4; ++it) {                                       \
      gload_lds16(gA + (size_t)(it * 32) * Kb + kb_, &sA[buf][it * 4096 + dbase]); \
      gload_lds16(gB + (size_t)(it * 32) * Kb + kb_, &sB[buf][it * 4096 + dbase]); \
    }                                                                      \
  } while (0)

  STAGE_G(0, 0);
  __syncthreads();

  const int swz = (lr15 & 7) << 4;
  for (int st = 0; st < nsteps; ++st) {
    if (st + 1 < nsteps) STAGE_G(cur ^ 1, st + 1);
    const char* pA = sA[cur];
    const char* pB = sB[cur];
    bf16x8 af[2][4], bfr[2][4];
    #pragma unroll
    for (int m = 0; m < 4; ++m) {
      const int ra = (wr * 64 + m * 16 + lr15) * 128;
      af[0][m] = *(const bf16x8*)(pA + ra + ((lg * 16) ^ swz));
      af[1][m] = *(const bf16x8*)(pA + ra + ((64 + lg * 16) ^ swz));
      const int rb = (wc * 64 + m * 16 + lr15) * 128;
      bfr[0][m] = *(const bf16x8*)(pB + rb + ((lg * 16) ^ swz));
      bfr[1][m] = *(const bf16x8*)(pB + rb + ((64 + lg * 16) ^ swz));
    }
    #pragma unroll
    for (int kh = 0; kh < 2; ++kh)
      #pragma unroll
      for (int m = 0; m < 4; ++m)
        #pragma unroll
        for (int n = 0; n < 4; ++n)
          acc[m][n] = MFMA_BF16(af[kh][m], bfr[kh][n], acc[m][n]);
    __syncthreads();
    cur ^= 1;
  }
#undef STAGE_G

  #pragma unroll
  for (int m = 0; m < 4; ++m) {
    #pragma unroll
    for (int n = 0; n < 4; ++n) {
      #pragma unroll
      for (int r = 0; r < 4; ++r) {
        const int grow = row0 + wr * 64 + m * 16 + lg * 4 + r;
        const int gcol = col0 + wc * 64 + n * 16 + lr15;
        const size_t idx = (size_t)grow * N + gcol;
        const float v = acc[m][n][r];
        if (EPI == 0) {
          Cb[idx] = __float2bfloat16(v);
        } else if (EPI == 1) {
          Cf[idx] = resid[idx] + v;
        } else {
          Cb[idx] = __float2bfloat16(v / (1.0f + __expf(-v)));
        }
      }
    }
  }
}

// ---------------- RoPE on q,k ----------------
__global__ __launch_bounds__(256)
void rope_qk(const __hip_bfloat16* __restrict__ qkv,
             __hip_bfloat16* __restrict__ Q, __hip_bfloat16* __restrict__ Kx)
{
  int idx = blockIdx.x * 256 + threadIdx.x;   // bits: i:5, h:4, s:11, b:1
  int i = idx & 31;
  int h = (idx >> 5) & 15;
  int s = (idx >> 9) & (S_LEN - 1);
  int b = idx >> 20;
  const size_t base = ((size_t)b * S_LEN + s) * 3072 + h * 64 + 2 * i;
  float qe = __bfloat162float(qkv[base]);
  float qo = __bfloat162float(qkv[base + 1]);
  float ke = __bfloat162float(qkv[base + 1024]);
  float ko = __bfloat162float(qkv[base + 1025]);
  float inv = __expf(-(2.0f * i) * (9.210340371976184f / 64.0f));
  float ang = (float)s * inv;
  float sn, cs;
  __sincosf(ang, &sn, &cs);
  const float sc = 0.125f;   // 1/sqrt(HD) folded into Q
  size_t qb = (((size_t)b * NH + h) * S_LEN + s) * HD + 2 * i;
  Q[qb]     = __float2bfloat16((qe * cs - qo * sn) * sc);
  Q[qb + 1] = __float2bfloat16((qo * cs + qe * sn) * sc);
  Kx[qb]     = __float2bfloat16(ke * cs - ko * sn);
  Kx[qb + 1] = __float2bfloat16(ko * cs + ke * sn);
}

// ---------------- V transpose ----------------
__global__ __launch_bounds__(256)
void v_transpose(const __hip_bfloat16* __restrict__ qkv, __hip_bfloat16* __restrict__ Vt)
{
  __shared__ __hip_bfloat16 t[64][72];
  const int s0 = blockIdx.x * 64;
  const int bh = blockIdx.y;
  const int b = bh >> 4, h = bh & 15;
  const int tid = threadIdx.x;
  const int c = tid & 63;
  #pragma unroll
  for (int r = 0; r < 16; ++r) {
    int srow = r * 4 + (tid >> 6);
    t[srow][c] = qkv[((size_t)b * S_LEN + s0 + srow) * 3072 + 2048 + h * 64 + c];
  }
  __syncthreads();
  #pragma unroll
  for (int r = 0; r < 16; ++r) {
    int drow = r * 4 + (tid >> 6);
    Vt[(((size_t)b * NH + h) * HD + drow) * S_LEN + s0 + c] = t[c][drow];
  }
}

__device__ __forceinline__ unsigned bf16pack2(float a, float b) {
  __hip_bfloat16 ha = __float2bfloat16(a), hb = __float2bfloat16(b);
  unsigned ua = *reinterpret_cast<unsigned short*>(&ha);
  unsigned ub = *reinterpret_cast<unsigned short*>(&hb);
  return ua | (ub << 16);
}

// ---------------- flash attention v3 (+setprio, no fmin) ----------------
__global__ __launch_bounds__(256, 4)
void flash_attn3(const __hip_bfloat16* __restrict__ Q,
                 const __hip_bfloat16* __restrict__ Kx,
                 const __hip_bfloat16* __restrict__ Vt,
                 __hip_bfloat16* __restrict__ attn)
{
  __shared__ __align__(16) char sK[2][8192];
  __shared__ __align__(16) char sV[2][8192];
  __shared__ __align__(16) char sP[4][2048];

  const int tid = threadIdx.x;
  const int w = tid >> 6;           // wave 0..3
  const int lane = tid & 63;
  const int lg = lane >> 4, lr = lane & 15;
  const int bid = blockIdx.x;
  const int bh = bid & 31;          // b*16+h
  const int b = bh >> 4, h = bh & 15;
  const int j = bid >> 5;           // 0..31
  const int m = j >> 3, a = j & 7;
  const int xm = (0x6170 >> (m << 2)) & 7;   // {0,7,1,6}: per-CU causal-load balance
  const int qb = m * 8 + (a ^ xm);
  const int q0 = qb * 64;
  const int nsteps = qb + 1;

  const char* Kb = (const char*)(Kx + (size_t)bh * S_LEN * HD);   // [S][64] bf16
  const char* Vb = (const char*)(Vt + (size_t)bh * HD * S_LEN);   // [64][S] bf16
  const __hip_bfloat16* Qp = Q + (size_t)bh * S_LEN * HD;

  const int q0w = q0 + w * 16;
  const bf16x8 qf0 = *(const bf16x8*)&Qp[(q0w + lr) * HD + lg * 8];
  const bf16x8 qf1 = *(const bf16x8*)&Qp[(q0w + lr) * HD + 32 + lg * 8];
  char* sPw = sP[w];
  const int swzr = (lr & 7) << 4;
  const int wbase = (tid & 192) << 4;     // wave*64 chunks *16 B

  f32x4 acc[4] = {};
  float lsum = 0.f;
  int cur = 0;

  #pragma unroll
  for (int i = 0; i < 2; ++i) {
    const int c = i * 256 + tid;
    const int row = c >> 3;
    const int scol = ((c & 7) << 4) ^ ((row & 7) << 4);
    gload_lds16(Kb + (size_t)row * 128 + scol, sK[0] + i * 4096 + wbase);
    gload_lds16(Vb + (size_t)row * (S_LEN * 2) + scol, sV[0] + i * 4096 + wbase);
  }
  __syncthreads();

  for (int st = 0; st < nsteps; ++st) {
    if (st + 1 < nsteps) {
      const int kn = (st + 1) * 64;
      #pragma unroll
      for (int i = 0; i < 2; ++i) {
        const int c = i * 256 + tid;
        const int row = c >> 3;
        const int scol = ((c & 7) << 4) ^ ((row & 7) << 4);
        gload_lds16(Kb + (size_t)(kn + row) * 128 + scol, sK[cur ^ 1] + i * 4096 + wbase);
        gload_lds16(Vb + (size_t)row * (S_LEN * 2) + (size_t)kn * 2 + scol, sV[cur ^ 1] + i * 4096 + wbase);
      }
    }
    const int k0 = st * 64;
    const char* pK = sK[cur];
    const char* pV = sV[cur];
    f32x4 sv[4];
    __builtin_amdgcn_s_setprio(1);
    #pragma unroll
    for (int t = 0; t < 4; ++t) {
      const int rb = (t * 16 + lr) * 128;
      const bf16x8 kf0 = *(const bf16x8*)(pK + rb + ((lg * 16) ^ swzr));
      const bf16x8 kf1 = *(const bf16x8*)(pK + rb + ((64 + lg * 16) ^ swzr));
      f32x4 z = {};
      z = MFMA_BF16(kf0, qf0, z);
      z = MFMA_BF16(kf1, qf1, z);
      sv[t] = z;
    }
    __builtin_amdgcn_s_setprio(0);
    const bool maskstep = (st == nsteps - 1);
    #pragma unroll
    for (int t = 0; t < 4; ++t) {
      float p[4];
      #pragma unroll
      for (int r = 0; r < 4; ++r) {
        float e = __expf(sv[t][r]);
        if (maskstep) {
          const int kg = k0 + t * 16 + lg * 4 + r;
          e = (kg <= q0w + lr) ? e : 0.f;
        }
        lsum += e;
        p[r] = e;
      }
      uint2 wv2;
      wv2.x = bf16pack2(p[0], p[1]);
      wv2.y = bf16pack2(p[2], p[3]);
      *(uint2*)(sPw + lr * 128 + ((t * 32 + lg * 8) ^ swzr)) = wv2;
    }
    asm volatile("s_waitcnt lgkmcnt(0)" ::: "memory");
    __builtin_amdgcn_sched_barrier(0);
    const bf16x8 pa0 = *(const bf16x8*)(sPw + lr * 128 + ((lg * 16) ^ swzr));
    const bf16x8 pa1 = *(const bf16x8*)(sPw + lr * 128 + ((64 + lg * 16) ^ swzr));
    __builtin_amdgcn_s_setprio(1);
    #pragma unroll
    for (int dt = 0; dt < 4; ++dt) {
      const int rb = (dt * 16 + lr) * 128;
      const bf16x8 vf0 = *(const bf16x8*)(pV + rb + ((lg * 16) ^ swzr));
      const bf16x8 vf1 = *(const bf16x8*)(pV + rb + ((64 + lg * 16) ^ swzr));
      acc[dt] = MFMA_BF16(pa0, vf0, acc[dt]);
      acc[dt] = MFMA_BF16(pa1, vf1, acc[dt]);
    }
    __builtin_amdgcn_s_setprio(0);
    __syncthreads();
    cur ^= 1;
  }

  lsum += __shfl_xor(lsum, 16);
  lsum += __shfl_xor(lsum, 32);
  #pragma unroll
  for (int r = 0; r < 4; ++r) {
    const float li = __shfl(lsum, lg * 4 + r);
    const float rli = 1.0f / li;
    const size_t rowb = ((size_t)b * S_LEN + q0w + lg * 4 + r) * DIMSZ + h * HD;
    #pragma unroll
    for (int dt = 0; dt < 4; ++dt)
      attn[rowb + dt * 16 + lr] = __float2bfloat16(acc[dt][r] * rli);
  }
}

extern "C" void kernel_launch(void* const* d_in, const int* in_sizes, int n_in,
                              void* d_out, int out_size, void* d_ws, size_t ws_size,
                              hipStream_t stream)
{
  const float* x      = (const float*)d_in[0];
  const float* w_in   = (const float*)d_in[1];
  const float* w_ff   = (const float*)d_in[2];
  const float* w_qkv  = (const float*)d_in[3];
  const float* w_out  = (const float*)d_in[4];
  const float* w_fc   = (const float*)d_in[5];
  const float* w_proj = (const float*)d_in[6];
  float* out = (float*)d_out;
  char* ws = (char*)d_ws;

  __hip_bfloat16* wq_b   = (__hip_bfloat16*)(ws);               // 6,291,456
  __hip_bfloat16* wo_b   = (__hip_bfloat16*)(ws + 6291456);     // 2,097,152
  __hip_bfloat16* wfc_b  = (__hip_bfloat16*)(ws + 8388608);     // 4,194,304
  __hip_bfloat16* wpr_b  = (__hip_bfloat16*)(ws + 12582912);    // 4,194,304
  __hip_bfloat16* h_b    = (__hip_bfloat16*)(ws + 16777216);    // 8,388,608
  __hip_bfloat16* qkv_b  = (__hip_bfloat16*)(ws + 25165824);    // 25,165,824
  __hip_bfloat16* attn_b = (__hip_bfloat16*)(ws + 25165824);    // reuse qkv[0:8M]
  __hip_bfloat16* hid_b  = (__hip_bfloat16*)(ws + 33554432);    // reuse qkv[8M:24M]
  __hip_bfloat16* Q_b    = (__hip_bfloat16*)(ws + 50331648);    // 8,388,608
  __hip_bfloat16* K_b    = (__hip_bfloat16*)(ws + 58720256);    // 8,388,608
  __hip_bfloat16* Vt_b   = (__hip_bfloat16*)(ws + 67108864);    // 8,388,608
  float*          x1     = (float*)(ws + 50331648);             // reuse Q+K after flash

  cast_all_kernel<<<8192, 256, 0, stream>>>(w_qkv, w_out, w_fc, w_proj, wq_b, wo_b, wfc_b, wpr_b);
  rmsnorm_kernel<<<4096, 256, 0, stream>>>(x, w_in, h_b);
  gemm256<0><<<dim3(192), 512, 0, stream>>>(h_b, wq_b, nullptr, qkv_b, nullptr, 3072, 1024, 12);
  rope_qk<<<2097152 / 256, 256, 0, stream>>>(qkv_b, Q_b, K_b);
  v_transpose<<<dim3(32, 32), 256, 0, stream>>>(qkv_b, Vt_b);
  flash_attn3<<<1024, 256, 0, stream>>>(Q_b, K_b, Vt_b, attn_b);
  gemm_bt2<1><<<dim3(1024 / 128, 4096 / 128), 256, 0, stream>>>(attn_b, wo_b, x1, nullptr, x, 1024, 1024);
  rmsnorm_kernel<<<4096, 256, 0, stream>>>(x1, w_ff, h_b);
  gemm256<2><<<dim3(128), 512, 0, stream>>>(h_b, wfc_b, nullptr, hid_b, nullptr, 2048, 1024, 8);
  gemm_bt2<1><<<dim3(1024 / 128, 4096 / 128), 256, 0, stream>>>(hid_b, wpr_b, out, nullptr, x1, 1024, 2048);
}

// Round 6
// 173.881 us; speedup vs baseline: 1.0806x; 1.0806x over previous
//
#include <hip/hip_runtime.h>
#include <hip/hip_bf16.h>
#include <cstdint>

#define DIMSZ 1024
#define S_LEN 2048
#define NH 16
#define HD 64

typedef __attribute__((ext_vector_type(4))) float f32x4;
typedef __attribute__((ext_vector_type(8))) __bf16 bf16x8;

#define MFMA_BF16(a,b,c) __builtin_amdgcn_mfma_f32_16x16x32_bf16((a),(b),(c),0,0,0)

__device__ __forceinline__ void gload_lds16(const void* g, void* l) {
  __builtin_amdgcn_global_load_lds(
      (const __attribute__((address_space(1))) unsigned int*)(uintptr_t)g,
      (__attribute__((address_space(3))) unsigned int*)(uintptr_t)l,
      16, 0, 0);
}

// ---------------- fused cast fp32 -> bf16 for all 4 weights ----------------
__global__ __launch_bounds__(256)
void cast_all_kernel(const float* __restrict__ s0, const float* __restrict__ s1,
                     const float* __restrict__ s2, const float* __restrict__ s3,
                     __hip_bfloat16* __restrict__ d0, __hip_bfloat16* __restrict__ d1,
                     __hip_bfloat16* __restrict__ d2, __hip_bfloat16* __restrict__ d3)
{
  int i = blockIdx.x * 256 + threadIdx.x;   // float4 index, total 2097152
  const float* s; __hip_bfloat16* d; int off;
  if (i < 786432)       { s = s0; d = d0; off = i; }
  else if (i < 1048576) { s = s1; d = d1; off = i - 786432; }
  else if (i < 1572864) { s = s2; d = d2; off = i - 1048576; }
  else                  { s = s3; d = d3; off = i - 1572864; }
  float4 v = ((const float4*)s)[off];
  __hip_bfloat16* o = d + (size_t)off * 4;
  o[0] = __float2bfloat16(v.x);
  o[1] = __float2bfloat16(v.y);
  o[2] = __float2bfloat16(v.z);
  o[3] = __float2bfloat16(v.w);
}

// ---------------- RMSNorm: fp32 row -> bf16 row ----------------
__global__ __launch_bounds__(256)
void rmsnorm_kernel(const float* __restrict__ x, const float* __restrict__ w,
                    __hip_bfloat16* __restrict__ out)
{
  int row = blockIdx.x;
  int tid = threadIdx.x;
  const float4 v = ((const float4*)(x + (size_t)row * DIMSZ))[tid];
  float ss = v.x*v.x + v.y*v.y + v.z*v.z + v.w*v.w;
  #pragma unroll
  for (int m = 32; m >= 1; m >>= 1) ss += __shfl_xor(ss, m);
  __shared__ float red[4];
  int wave = tid >> 6, lane = tid & 63;
  if (lane == 0) red[wave] = ss;
  __syncthreads();
  float tot = red[0] + red[1] + red[2] + red[3];
  float sc = rsqrtf(tot * (1.0f / DIMSZ) + 1e-6f);
  const float4 wv = ((const float4*)w)[tid];
  __hip_bfloat16* o = out + (size_t)row * DIMSZ + tid * 4;
  o[0] = __float2bfloat16(v.x * sc * wv.x);
  o[1] = __float2bfloat16(v.y * sc * wv.y);
  o[2] = __float2bfloat16(v.z * sc * wv.z);
  o[3] = __float2bfloat16(v.w * sc * wv.w);
}

// ---------------- GEMM v2: 128x128 2-phase, BK=64, dbuf, swizzled ----------------
template<int EPI>
__global__ __launch_bounds__(256, 2)
void gemm_bt2(const __hip_bfloat16* __restrict__ A,
              const __hip_bfloat16* __restrict__ Bw,
              float* __restrict__ Cf,
              __hip_bfloat16* __restrict__ Cb,
              const float* __restrict__ resid,
              int N, int K)
{
  __shared__ __align__(16) char sA[2][16384];   // [128 rows][128 B]
  __shared__ __align__(16) char sB[2][16384];
  const int tid = threadIdx.x;
  const int wave = tid >> 6, lane = tid & 63;
  const int lg = lane >> 4, lr15 = lane & 15;
  const int row0 = blockIdx.y * 128, col0 = blockIdx.x * 128;
  const int wr = wave >> 1, wc = wave & 1;
  f32x4 acc[4][4] = {};

  const size_t Kb = (size_t)K * 2;
  const int rown = tid >> 3;               // 0..31
  const int scol = ((tid & 7) << 4) ^ ((rown & 7) << 4);
  const char* gA = (const char*)A + (size_t)(row0 + rown) * Kb + scol;
  const char* gB = (const char*)Bw + (size_t)(col0 + rown) * Kb + scol;
  const int dbase = wave * 1024;

  const int nsteps = K >> 6;
  int cur = 0;

#define STAGE_G(buf, st) do {                                              \
    const size_t kb_ = (size_t)(st) * 128;                                 \
    _Pragma("unroll")                                                      \
    for (int it = 0; it < 4; ++it) {                                       \
      gload_lds16(gA + (size_t)(it * 32) * Kb + kb_, &sA[buf][it * 4096 + dbase]); \
      gload_lds16(gB + (size_t)(it * 32) * Kb + kb_, &sB[buf][it * 4096 + dbase]); \
    }                                                                      \
  } while (0)

  STAGE_G(0, 0);
  __syncthreads();

  const int swz = (lr15 & 7) << 4;
  for (int st = 0; st < nsteps; ++st) {
    if (st + 1 < nsteps) STAGE_G(cur ^ 1, st + 1);
    const char* pA = sA[cur];
    const char* pB = sB[cur];
    bf16x8 af[2][4], bfr[2][4];
    #pragma unroll
    for (int m = 0; m < 4; ++m) {
      const int ra = (wr * 64 + m * 16 + lr15) * 128;
      af[0][m] = *(const bf16x8*)(pA + ra + ((lg * 16) ^ swz));
      af[1][m] = *(const bf16x8*)(pA + ra + ((64 + lg * 16) ^ swz));
      const int rb = (wc * 64 + m * 16 + lr15) * 128;
      bfr[0][m] = *(const bf16x8*)(pB + rb + ((lg * 16) ^ swz));
      bfr[1][m] = *(const bf16x8*)(pB + rb + ((64 + lg * 16) ^ swz));
    }
    #pragma unroll
    for (int kh = 0; kh < 2; ++kh)
      #pragma unroll
      for (int m = 0; m < 4; ++m)
        #pragma unroll
        for (int n = 0; n < 4; ++n)
          acc[m][n] = MFMA_BF16(af[kh][m], bfr[kh][n], acc[m][n]);
    __syncthreads();
    cur ^= 1;
  }
#undef STAGE_G

  #pragma unroll
  for (int m = 0; m < 4; ++m) {
    #pragma unroll
    for (int n = 0; n < 4; ++n) {
      #pragma unroll
      for (int r = 0; r < 4; ++r) {
        const int grow = row0 + wr * 64 + m * 16 + lg * 4 + r;
        const int gcol = col0 + wc * 64 + n * 16 + lr15;
        const size_t idx = (size_t)grow * N + gcol;
        const float v = acc[m][n][r];
        if (EPI == 0) {
          Cb[idx] = __float2bfloat16(v);
        } else if (EPI == 1) {
          Cf[idx] = resid[idx] + v;
        } else {
          Cb[idx] = __float2bfloat16(v / (1.0f + __expf(-v)));
        }
      }
    }
  }
}

// ---------------- RoPE on q,k ----------------
__global__ __launch_bounds__(256)
void rope_qk(const __hip_bfloat16* __restrict__ qkv,
             __hip_bfloat16* __restrict__ Q, __hip_bfloat16* __restrict__ Kx)
{
  int idx = blockIdx.x * 256 + threadIdx.x;   // bits: i:5, h:4, s:11, b:1
  int i = idx & 31;
  int h = (idx >> 5) & 15;
  int s = (idx >> 9) & (S_LEN - 1);
  int b = idx >> 20;
  const size_t base = ((size_t)b * S_LEN + s) * 3072 + h * 64 + 2 * i;
  float qe = __bfloat162float(qkv[base]);
  float qo = __bfloat162float(qkv[base + 1]);
  float ke = __bfloat162float(qkv[base + 1024]);
  float ko = __bfloat162float(qkv[base + 1025]);
  float inv = __expf(-(2.0f * i) * (9.210340371976184f / 64.0f));
  float ang = (float)s * inv;
  float sn, cs;
  __sincosf(ang, &sn, &cs);
  const float sc = 0.125f;   // 1/sqrt(HD) folded into Q
  size_t qb = (((size_t)b * NH + h) * S_LEN + s) * HD + 2 * i;
  Q[qb]     = __float2bfloat16((qe * cs - qo * sn) * sc);
  Q[qb + 1] = __float2bfloat16((qo * cs + qe * sn) * sc);
  Kx[qb]     = __float2bfloat16(ke * cs - ko * sn);
  Kx[qb + 1] = __float2bfloat16(ko * cs + ke * sn);
}

// ---------------- V transpose ----------------
__global__ __launch_bounds__(256)
void v_transpose(const __hip_bfloat16* __restrict__ qkv, __hip_bfloat16* __restrict__ Vt)
{
  __shared__ __hip_bfloat16 t[64][72];
  const int s0 = blockIdx.x * 64;
  const int bh = blockIdx.y;
  const int b = bh >> 4, h = bh & 15;
  const int tid = threadIdx.x;
  const int c = tid & 63;
  #pragma unroll
  for (int r = 0; r < 16; ++r) {
    int srow = r * 4 + (tid >> 6);
    t[srow][c] = qkv[((size_t)b * S_LEN + s0 + srow) * 3072 + 2048 + h * 64 + c];
  }
  __syncthreads();
  #pragma unroll
  for (int r = 0; r < 16; ++r) {
    int drow = r * 4 + (tid >> 6);
    Vt[(((size_t)b * NH + h) * HD + drow) * S_LEN + s0 + c] = t[c][drow];
  }
}

__device__ __forceinline__ unsigned bf16pack2(float a, float b) {
  __hip_bfloat16 ha = __float2bfloat16(a), hb = __float2bfloat16(b);
  unsigned ua = *reinterpret_cast<unsigned short*>(&ha);
  unsigned ub = *reinterpret_cast<unsigned short*>(&hb);
  return ua | (ub << 16);
}

// ---------------- flash attention v4: 8 waves / 512 thr / 128 q-rows ----------
// Halves per-CU K/V staging bytes and barrier-drain count vs v3 (34 vs 66
// step-slots/CU) while keeping per-wave fragment math identical. KVBLK=64,
// double-buffered LDS staged via global_load_lds (inverse-swizzled source).
// Complementary qb pairing (round 0: even qb ascending; round 1: odd qb
// descending) keeps per-CU causal load ~constant with 2 blocks/CU.
__global__ __launch_bounds__(512, 4)
void flash_attn4(const __hip_bfloat16* __restrict__ Q,
                 const __hip_bfloat16* __restrict__ Kx,
                 const __hip_bfloat16* __restrict__ Vt,
                 __hip_bfloat16* __restrict__ attn)
{
  __shared__ __align__(16) char sK[2][8192];
  __shared__ __align__(16) char sV[2][8192];
  __shared__ __align__(16) char sP[8][2048];

  const int tid = threadIdx.x;
  const int w = tid >> 6;           // wave 0..7
  const int lane = tid & 63;
  const int lg = lane >> 4, lr = lane & 15;
  const int bid = blockIdx.x;
  const int bh = bid & 31;          // b*16+h
  const int b = bh >> 4, h = bh & 15;
  const int u = (bid >> 5) & 7;     // slot within dispatch round
  const int rnd = bid >> 8;         // 0 or 1
  const int qb = rnd == 0 ? (u << 1) : (15 - (u << 1));   // {0,2,..14} then {15,13,..1}
  const int q0 = qb << 7;           // *128
  const int nsteps = (qb << 1) + 2;

  const char* Kb = (const char*)(Kx + (size_t)bh * S_LEN * HD);   // [S][64] bf16
  const char* Vb = (const char*)(Vt + (size_t)bh * HD * S_LEN);   // [64][S] bf16
  const __hip_bfloat16* Qp = Q + (size_t)bh * S_LEN * HD;

  const int q0w = q0 + w * 16;
  const bf16x8 qf0 = *(const bf16x8*)&Qp[(q0w + lr) * HD + lg * 8];
  const bf16x8 qf1 = *(const bf16x8*)&Qp[(q0w + lr) * HD + 32 + lg * 8];
  char* sPw = sP[w];
  const int swzr = (lr & 7) << 4;
  // staging: 512 threads, 1 K-load + 1 V-load each (row = tid>>3 in 0..63)
  const int srow = tid >> 3;
  const int scol = ((tid & 7) << 4) ^ ((srow & 7) << 4);
  const int wbase = w << 10;        // wave-uniform LDS chunk

  f32x4 acc[4] = {};
  float lsum = 0.f;
  int cur = 0;

  gload_lds16(Kb + (size_t)srow * 128 + scol, sK[0] + wbase);
  gload_lds16(Vb + (size_t)srow * (S_LEN * 2) + scol, sV[0] + wbase);
  __syncthreads();

  for (int st = 0; st < nsteps; ++st) {
    if (st + 1 < nsteps) {
      const size_t kn = (size_t)(st + 1) * 64;
      gload_lds16(Kb + (kn + srow) * 128 + scol, sK[cur ^ 1] + wbase);
      gload_lds16(Vb + (size_t)srow * (S_LEN * 2) + kn * 2 + scol, sV[cur ^ 1] + wbase);
    }
    const int k0 = st * 64;
    const char* pK = sK[cur];
    const char* pV = sV[cur];
    f32x4 sv[4];
    __builtin_amdgcn_s_setprio(1);
    #pragma unroll
    for (int t = 0; t < 4; ++t) {
      const int rb = (t * 16 + lr) * 128;
      const bf16x8 kf0 = *(const bf16x8*)(pK + rb + ((lg * 16) ^ swzr));
      const bf16x8 kf1 = *(const bf16x8*)(pK + rb + ((64 + lg * 16) ^ swzr));
      f32x4 z = {};
      z = MFMA_BF16(kf0, qf0, z);
      z = MFMA_BF16(kf1, qf1, z);
      sv[t] = z;
    }
    __builtin_amdgcn_s_setprio(0);
    const bool maskstep = (st >= nsteps - 2);   // last two steps cross the diagonal
    #pragma unroll
    for (int t = 0; t < 4; ++t) {
      float p[4];
      #pragma unroll
      for (int r = 0; r < 4; ++r) {
        float e = __expf(sv[t][r]);
        if (maskstep) {
          const int kg = k0 + t * 16 + lg * 4 + r;
          e = (kg <= q0w + lr) ? e : 0.f;
        }
        lsum += e;
        p[r] = e;
      }
      uint2 wv2;
      wv2.x = bf16pack2(p[0], p[1]);
      wv2.y = bf16pack2(p[2], p[3]);
      *(uint2*)(sPw + lr * 128 + ((t * 32 + lg * 8) ^ swzr)) = wv2;
    }
    asm volatile("s_waitcnt lgkmcnt(0)" ::: "memory");
    __builtin_amdgcn_sched_barrier(0);
    const bf16x8 pa0 = *(const bf16x8*)(sPw + lr * 128 + ((lg * 16) ^ swzr));
    const bf16x8 pa1 = *(const bf16x8*)(sPw + lr * 128 + ((64 + lg * 16) ^ swzr));
    __builtin_amdgcn_s_setprio(1);
    #pragma unroll
    for (int dt = 0; dt < 4; ++dt) {
      const int rb = (dt * 16 + lr) * 128;
      const bf16x8 vf0 = *(const bf16x8*)(pV + rb + ((lg * 16) ^ swzr));
      const bf16x8 vf1 = *(const bf16x8*)(pV + rb + ((64 + lg * 16) ^ swzr));
      acc[dt] = MFMA_BF16(pa0, vf0, acc[dt]);
      acc[dt] = MFMA_BF16(pa1, vf1, acc[dt]);
    }
    __builtin_amdgcn_s_setprio(0);
    __syncthreads();     // drains vmcnt(0): next-step staging landed; dbuf safe
    cur ^= 1;
  }

  lsum += __shfl_xor(lsum, 16);
  lsum += __shfl_xor(lsum, 32);
  #pragma unroll
  for (int r = 0; r < 4; ++r) {
    const float li = __shfl(lsum, lg * 4 + r);
    const float rli = 1.0f / li;
    const size_t rowb = ((size_t)b * S_LEN + q0w + lg * 4 + r) * DIMSZ + h * HD;
    #pragma unroll
    for (int dt = 0; dt < 4; ++dt)
      attn[rowb + dt * 16 + lr] = __float2bfloat16(acc[dt][r] * rli);
  }
}

extern "C" void kernel_launch(void* const* d_in, const int* in_sizes, int n_in,
                              void* d_out, int out_size, void* d_ws, size_t ws_size,
                              hipStream_t stream)
{
  const float* x      = (const float*)d_in[0];
  const float* w_in   = (const float*)d_in[1];
  const float* w_ff   = (const float*)d_in[2];
  const float* w_qkv  = (const float*)d_in[3];
  const float* w_out  = (const float*)d_in[4];
  const float* w_fc   = (const float*)d_in[5];
  const float* w_proj = (const float*)d_in[6];
  float* out = (float*)d_out;
  char* ws = (char*)d_ws;

  __hip_bfloat16* wq_b   = (__hip_bfloat16*)(ws);               // 6,291,456
  __hip_bfloat16* wo_b   = (__hip_bfloat16*)(ws + 6291456);     // 2,097,152
  __hip_bfloat16* wfc_b  = (__hip_bfloat16*)(ws + 8388608);     // 4,194,304
  __hip_bfloat16* wpr_b  = (__hip_bfloat16*)(ws + 12582912);    // 4,194,304
  __hip_bfloat16* h_b    = (__hip_bfloat16*)(ws + 16777216);    // 8,388,608
  __hip_bfloat16* qkv_b  = (__hip_bfloat16*)(ws + 25165824);    // 25,165,824
  __hip_bfloat16* attn_b = (__hip_bfloat16*)(ws + 25165824);    // reuse qkv[0:8M]
  __hip_bfloat16* hid_b  = (__hip_bfloat16*)(ws + 33554432);    // reuse qkv[8M:24M]
  __hip_bfloat16* Q_b    = (__hip_bfloat16*)(ws + 50331648);    // 8,388,608
  __hip_bfloat16* K_b    = (__hip_bfloat16*)(ws + 58720256);    // 8,388,608
  __hip_bfloat16* Vt_b   = (__hip_bfloat16*)(ws + 67108864);    // 8,388,608
  float*          x1     = (float*)(ws + 50331648);             // reuse Q+K after flash

  cast_all_kernel<<<8192, 256, 0, stream>>>(w_qkv, w_out, w_fc, w_proj, wq_b, wo_b, wfc_b, wpr_b);
  rmsnorm_kernel<<<4096, 256, 0, stream>>>(x, w_in, h_b);
  gemm_bt2<0><<<dim3(3072 / 128, 4096 / 128), 256, 0, stream>>>(h_b, wq_b, nullptr, qkv_b, nullptr, 3072, 1024);
  rope_qk<<<2097152 / 256, 256, 0, stream>>>(qkv_b, Q_b, K_b);
  v_transpose<<<dim3(32, 32), 256, 0, stream>>>(qkv_b, Vt_b);
  flash_attn4<<<512, 512, 0, stream>>>(Q_b, K_b, Vt_b, attn_b);
  gemm_bt2<1><<<dim3(1024 / 128, 4096 / 128), 256, 0, stream>>>(attn_b, wo_b, x1, nullptr, x, 1024, 1024);
  rmsnorm_kernel<<<4096, 256, 0, stream>>>(x1, w_ff, h_b);
  gemm_bt2<2><<<dim3(2048 / 128, 4096 / 128), 256, 0, stream>>>(h_b, wfc_b, nullptr, hid_b, nullptr, 2048, 1024);
  gemm_bt2<1><<<dim3(1024 / 128, 4096 / 128), 256, 0, stream>>>(hid_b, wpr_b, out, nullptr, x1, 1024, 2048);
}